// Round 21
// baseline (38.634 us; speedup 1.0000x reference)
//
#include <hip/hip_runtime.h>
#include <hip/hip_bf16.h>

// GAT layer, B=8 N=1024 IN=128 H=4 D=32. Inputs f32, OUTPUT f32.
// Base = round-19 (37.5 us best). Single mechanism this round: SORTED-ORDER
// MATERIALIZATION — k_rank scatters each key's 128B h-row into hg[rank]
// (and packs t/e1/e2 into one float4), so k_comb's sums + boundary loops
// read CONSECUTIVE rows (8 contiguous cache lines per wave-instr instead of
// scattered gathers) and the kI indirection disappears.
//
// kA    : h = x@W^T via MFMA 16x16x32 bf16 (x split hi+lo bf16; W bf16).
//         Epilogue: s/t/e1/e2 per (row,head) transposed [h][bn].
// k_rank: LDS-staged split-loop u64 rank; scatter packed{t,e1,e2} (16B) and
//         the key's h row (128B, 2 threads x 64B) into sorted order.
// k_comb: stages packed, computes chunk sums in-block from hg (coalesced),
//         8-wave shuffle scan, search once per 8-lane group + uniform
//         16-iter boundary-chunk combine reading hg (coalesced).

#define B_   8
#define N_   1024
#define BN   (B_ * N_)
#define IND  128
#define H_   4
#define D_   32
#define NEG  0.2f
#define CH   16
#define NCH  (N_ / CH)       // 64
#define QB   64              // queries per k_comb block

typedef float float4_ __attribute__((ext_vector_type(4)));
typedef short short8_ __attribute__((ext_vector_type(8)));

__device__ __forceinline__ float bf2f(ushort u) {
    union { unsigned int i; float f; } v; v.i = ((unsigned int)u) << 16; return v.f;
}
__device__ __forceinline__ ushort f2bf(float f) {
    union { float f; unsigned int i; } v; v.f = f;
    unsigned int lsb = (v.i >> 16) & 1u;
    v.i += 0x7fffu + lsb;
    return (ushort)(v.i >> 16);
}
__device__ __forceinline__ unsigned int orderable(float f) {
    unsigned int u = __float_as_uint(f);
    return (u & 0x80000000u) ? ~u : (u | 0x80000000u);
}
__device__ __forceinline__ short8_ pack_hi(float4_ a, float4_ b) {
    short8_ r;
    r[0] = (short)f2bf(a[0]); r[1] = (short)f2bf(a[1]);
    r[2] = (short)f2bf(a[2]); r[3] = (short)f2bf(a[3]);
    r[4] = (short)f2bf(b[0]); r[5] = (short)f2bf(b[1]);
    r[6] = (short)f2bf(b[2]); r[7] = (short)f2bf(b[3]);
    return r;
}
__device__ __forceinline__ void split_bf(float4_ a, float4_ b, short8_& hi, short8_& lo) {
    #pragma unroll
    for (int j = 0; j < 4; ++j) {
        ushort h0 = f2bf(a[j]); hi[j]     = (short)h0; lo[j]     = (short)f2bf(a[j] - bf2f(h0));
        ushort h1 = f2bf(b[j]); hi[j + 4] = (short)h1; lo[j + 4] = (short)f2bf(b[j] - bf2f(h1));
    }
}

// ---------------- Kernel A: MFMA GEMM + alpha epilogue --------------------
// grid = 256 blocks x 256 thr (4 waves). Block: 32 rows (2 M-tiles of 16).
__global__ __launch_bounds__(256) void k_gemm_alpha(
    const float* __restrict__ x,      // [B*N,128]
    const float* __restrict__ alive,  // [B*N]
    const float* __restrict__ W,      // [128,128]
    const float* __restrict__ a_src,  // [128]
    const float* __restrict__ a_dst,  // [128]
    float* __restrict__ h_ws,         // [B*N,128]
    float* __restrict__ sT,           // [H][BN]
    float* __restrict__ tT,           // [H][BN]
    float* __restrict__ e1T,          // [H][BN]
    float* __restrict__ e2T)          // [H][BN]
{
    __shared__ float hs[32][132];     // 16.9 KB
    __shared__ float asrc[IND], adst[IND];

    const int tid = threadIdx.x;
    const int wv  = tid >> 6;
    const int ln  = tid & 63;
    const int l15 = ln & 15;
    const int lg  = ln >> 4;
    const int rbase = blockIdx.x * 32;

    if (tid < IND) { asrc[tid] = a_src[tid]; adst[tid] = a_dst[tid]; }

    short8_ bf[2][4];
    #pragma unroll
    for (int t = 0; t < 2; ++t) {
        const float* wr = &W[(size_t)((wv * 2 + t) * 16 + l15) * IND + lg * 8];
        #pragma unroll
        for (int ks = 0; ks < 4; ++ks) {
            float4_ v0 = *reinterpret_cast<const float4_*>(wr + ks * 32);
            float4_ v1 = *reinterpret_cast<const float4_*>(wr + ks * 32 + 4);
            bf[t][ks] = pack_hi(v0, v1);
        }
    }

    float4_ acc[2][2];
    #pragma unroll
    for (int mt = 0; mt < 2; ++mt) {
        const float* xr = &x[(size_t)(rbase + mt * 16 + l15) * IND + lg * 8];
        short8_ ahi[4], alo[4];
        #pragma unroll
        for (int ks = 0; ks < 4; ++ks) {
            float4_ v0 = *reinterpret_cast<const float4_*>(xr + ks * 32);
            float4_ v1 = *reinterpret_cast<const float4_*>(xr + ks * 32 + 4);
            split_bf(v0, v1, ahi[ks], alo[ks]);
        }
        #pragma unroll
        for (int t = 0; t < 2; ++t) {
            float4_ a = {0.f, 0.f, 0.f, 0.f};
            #pragma unroll
            for (int ks = 0; ks < 4; ++ks) {
                a = __builtin_amdgcn_mfma_f32_16x16x32_bf16(ahi[ks], bf[t][ks], a, 0, 0, 0);
                a = __builtin_amdgcn_mfma_f32_16x16x32_bf16(alo[ks], bf[t][ks], a, 0, 0, 0);
            }
            acc[mt][t] = a;
        }
    }

    #pragma unroll
    for (int mt = 0; mt < 2; ++mt)
        #pragma unroll
        for (int t = 0; t < 2; ++t) {
            const int col = (wv * 2 + t) * 16 + l15;
            #pragma unroll
            for (int r = 0; r < 4; ++r)
                hs[mt * 16 + lg * 4 + r][col] = acc[mt][t][r];
        }
    __syncthreads();

    #pragma unroll
    for (int i = tid; i < 1024; i += 256) {
        int row = i >> 5, c4 = (i & 31) * 4;
        *reinterpret_cast<float4_*>(&h_ws[(size_t)(rbase + row) * IND + c4]) =
            *reinterpret_cast<const float4_*>(&hs[row][c4]);
    }

    if (tid < 128) {
        const int row = tid >> 2, hh = tid & 3;
        const float* hr = &hs[row][hh * 32];
        float s = 0.f, tt = 0.f;
        #pragma unroll
        for (int d = 0; d < 32; ++d) {
            s  = fmaf(hr[d], asrc[hh * 32 + d], s);
            tt = fmaf(hr[d], adst[hh * 32 + d], tt);
        }
        const int grow = rbase + row;
        const int idx  = hh * BN + grow;
        sT[idx] = s;
        tT[idx] = tt;
        float am = (alive[grow] >= 0.5f) ? 1.f : 0.f;
        e1T[idx] = am * __expf(tt);
        e2T[idx] = am * __expf(NEG * tt);
    }
}

// ---------------- Kernel 2: split-loop rank + sorted materialization ------
// grid = (8, H, B) = 256 blocks, 256 threads. Block owns 128 keys; each key
// ranked by TWO threads (own = tid&127, half = tid>>7), each scanning half
// the staged table. Both threads then know the full rank and scatter the
// key's h row (64B each) into hg[rank]; half 0 also writes packed{t,e1,e2}.
__global__ __launch_bounds__(256) void k_rank(
    const float* __restrict__ tT,
    const float* __restrict__ e1T,
    const float* __restrict__ e2T,
    const float* __restrict__ h_ws,
    float4_* __restrict__ packed,   // [32][N] {t, e1, e2, -}
    float* __restrict__ hg)         // [32][N][32] h rows in sorted order
{
    __shared__ unsigned long long keys[N_];   // 8 KB
    __shared__ int part[2][128];
    const int h = blockIdx.y, b = blockIdx.z;
    const int base = h * BN + b * N_;
    for (int i = threadIdx.x; i < N_; i += 256) {
        unsigned int u = orderable(tT[base + i]);
        keys[i] = ((unsigned long long)u << 32) | (unsigned int)i;
    }
    __syncthreads();

    const int own  = threadIdx.x & 127;
    const int half = threadIdx.x >> 7;
    const int i0   = blockIdx.x * 128 + own;
    const unsigned long long mk = keys[i0];
    int rank = 0;
    const ulonglong2* k2p = reinterpret_cast<const ulonglong2*>(keys) + half * 256;
    #pragma unroll 8
    for (int j = 0; j < 256; ++j) {
        ulonglong2 kk = k2p[j];           // broadcast LDS read (wave-uniform)
        rank += (int)(kk.x < mk) + (int)(kk.y < mk);
    }
    part[half][own] = rank;
    __syncthreads();
    rank += part[1 - half][own];

    const int o = (b * H_ + h) * N_ + rank;
    if (!half) {
        float4_ pk;
        pk[0] = tT[base + i0];
        pk[1] = e1T[base + i0];
        pk[2] = e2T[base + i0];
        pk[3] = 0.f;
        packed[o] = pk;
    }
    // copy this key's h row (head h): 128B total, 64B per half
    const float4_* src = reinterpret_cast<const float4_*>(
        &h_ws[(size_t)(b * N_ + i0) * IND + h * D_ + half * 16]);
    float4_* dst = reinterpret_cast<float4_*>(&hg[(size_t)o * D_ + half * 16]);
    #pragma unroll
    for (int u = 0; u < 4; ++u) dst[u] = src[u];
}

// ---------------- Kernel 3: sums + scan + per-query combine ---------------
// grid = (N/QB, H, B), 512 threads: 64 queries x 8 dim-groups.
// Chunk sums in-block (1 cell/thread) from hg — consecutive-row reads.
__global__ __launch_bounds__(512) void k_comb(
    const float* __restrict__ hg,
    const float* __restrict__ sT,
    const float4_* __restrict__ packed,
    float* __restrict__ out)
{
    __shared__ float tS[N_];
    __shared__ float e1S[N_], e2S[N_];
    __shared__ float pre2[NCH + 1][36];
    __shared__ float suf1[NCH + 2][36];
    __shared__ float dpre2[NCH + 1], dsuf1[NCH + 2];

    const int h = blockIdx.y, b = blockIdx.z, qb = blockIdx.x;
    const int bhi = b * H_ + h;
    const int so  = bhi * N_;
    const int tid = threadIdx.x;

    for (int i = tid; i < N_; i += 512) {
        const float4_ pk = packed[so + i];
        tS[i]  = pk[0];
        e1S[i] = pk[1];
        e2S[i] = pk[2];
    }
    __syncthreads();

    // chunk sums in-block: 512 threads = 512 cells (cc 0..63, dg 0..7)
    {
        const int cc = tid >> 3, dg = tid & 7;
        float4_ a1 = {0.f, 0.f, 0.f, 0.f}, a2 = {0.f, 0.f, 0.f, 0.f};
        #pragma unroll
        for (int jj = 0; jj < CH; ++jj) {
            const int j = cc * CH + jj;
            const float4_ hv = *reinterpret_cast<const float4_*>(
                &hg[(size_t)(so + j) * D_ + dg * 4]);
            a1 += e1S[j] * hv;
            a2 += e2S[j] * hv;
        }
        #pragma unroll
        for (int u = 0; u < 4; ++u) {
            pre2[cc + 1][dg * 4 + u] = a2[u];
            suf1[cc][dg * 4 + u]     = a1[u];
        }
        if (tid < NCH) {
            float s2 = 0.f;
            #pragma unroll
            for (int jj = 0; jj < CH; ++jj) s2 += e2S[tid * CH + jj];
            dpre2[tid + 1] = s2;
        } else if (tid < 2 * NCH) {
            const int c2 = tid - NCH;
            float s1 = 0.f;
            #pragma unroll
            for (int jj = 0; jj < CH; ++jj) s1 += e1S[c2 * CH + jj];
            dsuf1[c2] = s1;
        }
    }
    __syncthreads();

    // in-block scans: waves 0-3 prefix, waves 4-7 suffix
    {
        const int wv = tid >> 6, lane = tid & 63;
        if (wv < 4) {
            for (int d = wv; d < D_; d += 4) {
                float v = pre2[lane + 1][d];
                #pragma unroll
                for (int off = 1; off < 64; off <<= 1) {
                    float n = __shfl_up(v, off);
                    if (lane >= off) v += n;
                }
                pre2[lane + 1][d] = v;
                if (lane == 0) pre2[0][d] = 0.f;
            }
            if (wv == 0) {
                float v = dpre2[lane + 1];
                #pragma unroll
                for (int off = 1; off < 64; off <<= 1) {
                    float n = __shfl_up(v, off);
                    if (lane >= off) v += n;
                }
                dpre2[lane + 1] = v;
                if (lane == 0) dpre2[0] = 0.f;
            }
        } else {
            for (int d = wv - 4; d < D_; d += 4) {
                float v = suf1[lane][d];
                #pragma unroll
                for (int off = 1; off < 64; off <<= 1) {
                    float n = __shfl_down(v, off);
                    if (lane < 64 - off) v += n;
                }
                suf1[lane][d] = v;
                if (lane == 0) { suf1[NCH][d] = 0.f; suf1[NCH + 1][d] = 0.f; }
            }
            if (wv == 4) {
                float v = dsuf1[lane];
                #pragma unroll
                for (int off = 1; off < 64; off <<= 1) {
                    float n = __shfl_down(v, off);
                    if (lane < 64 - off) v += n;
                }
                dsuf1[lane] = v;
                if (lane == 0) { dsuf1[NCH] = 0.f; dsuf1[NCH + 1] = 0.f; }
            }
        }
    }
    __syncthreads();

    const int ql  = tid >> 3;
    const int sub = tid & 7;
    const int ln  = tid & 63;
    const int q   = qb * QB + ql;

    const float s  = sT[h * BN + b * N_ + q];
    const float A  = __expf(s);
    const float Bv = __expf(NEG * s);

    // binary search once per query group (lane sub==0), broadcast via shfl
    int p = 0;
    if (sub == 0) {
        const float tau = -s;
        int lo = 0, hi = N_;
        #pragma unroll
        for (int it = 0; it < 10; ++it) {
            int mid = (lo + hi) >> 1;
            if (tS[mid] >= tau) hi = mid; else lo = mid + 1;
        }
        p = lo;
    }
    p = __shfl(p, ln & 56);
    const int cp = p >> 4;

    // table part + uniform 16-iter boundary-chunk loop (weight select)
    float4_ acc = A  * (*reinterpret_cast<const float4_*>(&suf1[cp + 1][sub * 4]))
                + Bv * (*reinterpret_cast<const float4_*>(&pre2[cp][sub * 4]));
    float den = A * dsuf1[cp + 1] + Bv * dpre2[cp];
    if (cp < NCH) {
        #pragma unroll
        for (int jj = 0; jj < CH; ++jj) {
            const int j = (cp << 4) + jj;
            const float w = (j < p) ? Bv * e2S[j] : A * e1S[j];
            const float4_ hv = *reinterpret_cast<const float4_*>(
                &hg[(size_t)(so + j) * D_ + sub * 4]);
            acc += w * hv;
            den += w;
        }
    }

    const float inv = (den > 0.f) ? 1.f / den : 0.f;
    float4_ r = acc * inv;
    *reinterpret_cast<float4_*>(&out[(size_t)(b * N_ + q) * IND + h * D_ + sub * 4]) = r;
}

extern "C" void kernel_launch(void* const* d_in, const int* in_sizes, int n_in,
                              void* d_out, int out_size, void* d_ws, size_t ws_size,
                              hipStream_t stream) {
    const float* x     = (const float*)d_in[0];
    const float* alive = (const float*)d_in[1];
    const float* W     = (const float*)d_in[2];
    const float* a_src = (const float*)d_in[3];
    const float* a_dst = (const float*)d_in[4];
    float* out = (float*)d_out;

    float*   h_ws   = (float*)d_ws;                 // BN*128 (4 MB)
    float*   sT     = h_ws + (size_t)BN * IND;      // [H][BN]
    float*   tT     = sT  + (size_t)H_ * BN;
    float*   e1T    = tT  + (size_t)H_ * BN;
    float*   e2T    = e1T + (size_t)H_ * BN;
    float4_* packed = (float4_*)(e2T + (size_t)H_ * BN);  // [32][N] x 16B
    float*   hg     = (float*)(packed + 32 * N_);         // [32][N][32] (4 MB)
    // total ~9.5 MB

    k_gemm_alpha<<<BN / 32, 256, 0, stream>>>(x, alive, W, a_src, a_dst,
                                              h_ws, sT, tT, e1T, e2T);

    dim3 g2(N_ / 128, H_, B_);
    k_rank<<<g2, 256, 0, stream>>>(tT, e1T, e2T, h_ws, packed, hg);

    dim3 g4(N_ / QB, H_, B_);
    k_comb<<<g4, 512, 0, stream>>>(hg, sT, packed, out);
}

// Round 22
// 37.507 us; speedup vs baseline: 1.0300x; 1.0300x over previous
//
#include <hip/hip_runtime.h>
#include <hip/hip_bf16.h>

// GAT layer, B=8 N=1024 IN=128 H=4 D=32. Inputs f32, OUTPUT f32.
// Base = round-19 (37.5 us best; R21's hg materialization reverted).
// Single change vs R19: PACKED SCATTER — k_rank writes one float4
// {t, e1, e2, bitcast(kI)} per key instead of 4 separate scalar scatters;
// k_comb stages one 16B stream instead of 4. h gathers unchanged (via kI).
//
// kA    : h = x@W^T via MFMA 16x16x32 bf16 (x split hi+lo bf16; W bf16).
//         Epilogue: s/t/e1/e2 per (row,head) transposed [h][bn].
// k_rank: LDS-staged split-loop u64 rank (2 threads/key, half table each),
//         scatter packed{t,e1,e2,kI} into sorted order.
// k_comb: stages packed, computes chunk sums in-block (1 cell/thread),
//         8-wave shuffle scan, search once per 8-lane group + uniform
//         16-iter boundary-chunk combine (weight select), gathers via kI.

#define B_   8
#define N_   1024
#define BN   (B_ * N_)
#define IND  128
#define H_   4
#define D_   32
#define NEG  0.2f
#define CH   16
#define NCH  (N_ / CH)       // 64
#define QB   64              // queries per k_comb block

typedef float float4_ __attribute__((ext_vector_type(4)));
typedef short short8_ __attribute__((ext_vector_type(8)));

__device__ __forceinline__ float bf2f(ushort u) {
    union { unsigned int i; float f; } v; v.i = ((unsigned int)u) << 16; return v.f;
}
__device__ __forceinline__ ushort f2bf(float f) {
    union { float f; unsigned int i; } v; v.f = f;
    unsigned int lsb = (v.i >> 16) & 1u;
    v.i += 0x7fffu + lsb;
    return (ushort)(v.i >> 16);
}
__device__ __forceinline__ unsigned int orderable(float f) {
    unsigned int u = __float_as_uint(f);
    return (u & 0x80000000u) ? ~u : (u | 0x80000000u);
}
__device__ __forceinline__ short8_ pack_hi(float4_ a, float4_ b) {
    short8_ r;
    r[0] = (short)f2bf(a[0]); r[1] = (short)f2bf(a[1]);
    r[2] = (short)f2bf(a[2]); r[3] = (short)f2bf(a[3]);
    r[4] = (short)f2bf(b[0]); r[5] = (short)f2bf(b[1]);
    r[6] = (short)f2bf(b[2]); r[7] = (short)f2bf(b[3]);
    return r;
}
__device__ __forceinline__ void split_bf(float4_ a, float4_ b, short8_& hi, short8_& lo) {
    #pragma unroll
    for (int j = 0; j < 4; ++j) {
        ushort h0 = f2bf(a[j]); hi[j]     = (short)h0; lo[j]     = (short)f2bf(a[j] - bf2f(h0));
        ushort h1 = f2bf(b[j]); hi[j + 4] = (short)h1; lo[j + 4] = (short)f2bf(b[j] - bf2f(h1));
    }
}

// ---------------- Kernel A: MFMA GEMM + alpha epilogue --------------------
// grid = 256 blocks x 256 thr (4 waves). Block: 32 rows (2 M-tiles of 16).
__global__ __launch_bounds__(256) void k_gemm_alpha(
    const float* __restrict__ x,      // [B*N,128]
    const float* __restrict__ alive,  // [B*N]
    const float* __restrict__ W,      // [128,128]
    const float* __restrict__ a_src,  // [128]
    const float* __restrict__ a_dst,  // [128]
    float* __restrict__ h_ws,         // [B*N,128]
    float* __restrict__ sT,           // [H][BN]
    float* __restrict__ tT,           // [H][BN]
    float* __restrict__ e1T,          // [H][BN]
    float* __restrict__ e2T)          // [H][BN]
{
    __shared__ float hs[32][132];     // 16.9 KB
    __shared__ float asrc[IND], adst[IND];

    const int tid = threadIdx.x;
    const int wv  = tid >> 6;
    const int ln  = tid & 63;
    const int l15 = ln & 15;
    const int lg  = ln >> 4;
    const int rbase = blockIdx.x * 32;

    if (tid < IND) { asrc[tid] = a_src[tid]; adst[tid] = a_dst[tid]; }

    short8_ bf[2][4];
    #pragma unroll
    for (int t = 0; t < 2; ++t) {
        const float* wr = &W[(size_t)((wv * 2 + t) * 16 + l15) * IND + lg * 8];
        #pragma unroll
        for (int ks = 0; ks < 4; ++ks) {
            float4_ v0 = *reinterpret_cast<const float4_*>(wr + ks * 32);
            float4_ v1 = *reinterpret_cast<const float4_*>(wr + ks * 32 + 4);
            bf[t][ks] = pack_hi(v0, v1);
        }
    }

    float4_ acc[2][2];
    #pragma unroll
    for (int mt = 0; mt < 2; ++mt) {
        const float* xr = &x[(size_t)(rbase + mt * 16 + l15) * IND + lg * 8];
        short8_ ahi[4], alo[4];
        #pragma unroll
        for (int ks = 0; ks < 4; ++ks) {
            float4_ v0 = *reinterpret_cast<const float4_*>(xr + ks * 32);
            float4_ v1 = *reinterpret_cast<const float4_*>(xr + ks * 32 + 4);
            split_bf(v0, v1, ahi[ks], alo[ks]);
        }
        #pragma unroll
        for (int t = 0; t < 2; ++t) {
            float4_ a = {0.f, 0.f, 0.f, 0.f};
            #pragma unroll
            for (int ks = 0; ks < 4; ++ks) {
                a = __builtin_amdgcn_mfma_f32_16x16x32_bf16(ahi[ks], bf[t][ks], a, 0, 0, 0);
                a = __builtin_amdgcn_mfma_f32_16x16x32_bf16(alo[ks], bf[t][ks], a, 0, 0, 0);
            }
            acc[mt][t] = a;
        }
    }

    #pragma unroll
    for (int mt = 0; mt < 2; ++mt)
        #pragma unroll
        for (int t = 0; t < 2; ++t) {
            const int col = (wv * 2 + t) * 16 + l15;
            #pragma unroll
            for (int r = 0; r < 4; ++r)
                hs[mt * 16 + lg * 4 + r][col] = acc[mt][t][r];
        }
    __syncthreads();

    #pragma unroll
    for (int i = tid; i < 1024; i += 256) {
        int row = i >> 5, c4 = (i & 31) * 4;
        *reinterpret_cast<float4_*>(&h_ws[(size_t)(rbase + row) * IND + c4]) =
            *reinterpret_cast<const float4_*>(&hs[row][c4]);
    }

    if (tid < 128) {
        const int row = tid >> 2, hh = tid & 3;
        const float* hr = &hs[row][hh * 32];
        float s = 0.f, tt = 0.f;
        #pragma unroll
        for (int d = 0; d < 32; ++d) {
            s  = fmaf(hr[d], asrc[hh * 32 + d], s);
            tt = fmaf(hr[d], adst[hh * 32 + d], tt);
        }
        const int grow = rbase + row;
        const int idx  = hh * BN + grow;
        sT[idx] = s;
        tT[idx] = tt;
        float am = (alive[grow] >= 0.5f) ? 1.f : 0.f;
        e1T[idx] = am * __expf(tt);
        e2T[idx] = am * __expf(NEG * tt);
    }
}

// ---------------- Kernel 2: split-loop LDS rank + packed scatter ----------
// grid = (8, H, B) = 256 blocks, 256 threads. Block owns 128 keys; each key
// ranked by TWO threads (own = tid&127, half = tid>>7), each scanning half
// the staged table. Partials combined in LDS; half 0 writes ONE float4
// {t, e1, e2, bitcast(idx)} to the sorted slot.
__global__ __launch_bounds__(256) void k_rank(
    const float* __restrict__ tT,
    const float* __restrict__ e1T,
    const float* __restrict__ e2T,
    float4_* __restrict__ packed)   // [32][N] {t, e1, e2, idx}
{
    __shared__ unsigned long long keys[N_];   // 8 KB
    __shared__ int part[128];
    const int h = blockIdx.y, b = blockIdx.z;
    const int base = h * BN + b * N_;
    for (int i = threadIdx.x; i < N_; i += 256) {
        unsigned int u = orderable(tT[base + i]);
        keys[i] = ((unsigned long long)u << 32) | (unsigned int)i;
    }
    __syncthreads();

    const int own  = threadIdx.x & 127;
    const int half = threadIdx.x >> 7;
    const int i0   = blockIdx.x * 128 + own;
    const unsigned long long mk = keys[i0];
    int rank = 0;
    const ulonglong2* k2p = reinterpret_cast<const ulonglong2*>(keys) + half * 256;
    #pragma unroll 8
    for (int j = 0; j < 256; ++j) {
        ulonglong2 kk = k2p[j];           // broadcast LDS read (wave-uniform)
        rank += (int)(kk.x < mk) + (int)(kk.y < mk);
    }
    if (half) part[own] = rank;
    __syncthreads();
    if (!half) {
        rank += part[own];
        const int o = (b * H_ + h) * N_ + rank;
        float4_ pk;
        pk[0] = tT[base + i0];
        pk[1] = e1T[base + i0];
        pk[2] = e2T[base + i0];
        pk[3] = __int_as_float(i0);
        packed[o] = pk;
    }
}

// ---------------- Kernel 3: sums + scan + per-query combine ---------------
// grid = (N/QB, H, B), 512 threads: 64 queries x 8 dim-groups.
// Chunk sums computed IN-BLOCK (1 cell/thread); h gathered via kI.
__global__ __launch_bounds__(512) void k_comb(
    const float* __restrict__ h_ws,
    const float* __restrict__ sT,
    const float4_* __restrict__ packed,
    float* __restrict__ out)
{
    __shared__ float tS[N_];
    __shared__ int   kI[N_];
    __shared__ float e1S[N_], e2S[N_];
    __shared__ float pre2[NCH + 1][36];
    __shared__ float suf1[NCH + 2][36];
    __shared__ float dpre2[NCH + 1], dsuf1[NCH + 2];

    const int h = blockIdx.y, b = blockIdx.z, qb = blockIdx.x;
    const int bhi = b * H_ + h;
    const int so  = bhi * N_;
    const int tid = threadIdx.x;

    for (int i = tid; i < N_; i += 512) {
        const float4_ pk = packed[so + i];
        tS[i]  = pk[0];
        e1S[i] = pk[1];
        e2S[i] = pk[2];
        kI[i]  = __float_as_int(pk[3]);
    }
    __syncthreads();

    // chunk sums in-block: 512 threads = 512 cells (cc 0..63, dg 0..7)
    {
        const int cc = tid >> 3, dg = tid & 7;
        float4_ a1 = {0.f, 0.f, 0.f, 0.f}, a2 = {0.f, 0.f, 0.f, 0.f};
        #pragma unroll
        for (int jj = 0; jj < CH; ++jj) {
            const int j = cc * CH + jj;
            const float4_ hv = *reinterpret_cast<const float4_*>(
                &h_ws[(size_t)(b * N_ + kI[j]) * IND + h * D_ + dg * 4]);
            a1 += e1S[j] * hv;
            a2 += e2S[j] * hv;
        }
        #pragma unroll
        for (int u = 0; u < 4; ++u) {
            pre2[cc + 1][dg * 4 + u] = a2[u];
            suf1[cc][dg * 4 + u]     = a1[u];
        }
        if (tid < NCH) {
            float s2 = 0.f;
            #pragma unroll
            for (int jj = 0; jj < CH; ++jj) s2 += e2S[tid * CH + jj];
            dpre2[tid + 1] = s2;
        } else if (tid < 2 * NCH) {
            const int c2 = tid - NCH;
            float s1 = 0.f;
            #pragma unroll
            for (int jj = 0; jj < CH; ++jj) s1 += e1S[c2 * CH + jj];
            dsuf1[c2] = s1;
        }
    }
    __syncthreads();

    // in-block scans: waves 0-3 prefix, waves 4-7 suffix
    {
        const int wv = tid >> 6, lane = tid & 63;
        if (wv < 4) {
            for (int d = wv; d < D_; d += 4) {
                float v = pre2[lane + 1][d];
                #pragma unroll
                for (int off = 1; off < 64; off <<= 1) {
                    float n = __shfl_up(v, off);
                    if (lane >= off) v += n;
                }
                pre2[lane + 1][d] = v;
                if (lane == 0) pre2[0][d] = 0.f;
            }
            if (wv == 0) {
                float v = dpre2[lane + 1];
                #pragma unroll
                for (int off = 1; off < 64; off <<= 1) {
                    float n = __shfl_up(v, off);
                    if (lane >= off) v += n;
                }
                dpre2[lane + 1] = v;
                if (lane == 0) dpre2[0] = 0.f;
            }
        } else {
            for (int d = wv - 4; d < D_; d += 4) {
                float v = suf1[lane][d];
                #pragma unroll
                for (int off = 1; off < 64; off <<= 1) {
                    float n = __shfl_down(v, off);
                    if (lane < 64 - off) v += n;
                }
                suf1[lane][d] = v;
                if (lane == 0) { suf1[NCH][d] = 0.f; suf1[NCH + 1][d] = 0.f; }
            }
            if (wv == 4) {
                float v = dsuf1[lane];
                #pragma unroll
                for (int off = 1; off < 64; off <<= 1) {
                    float n = __shfl_down(v, off);
                    if (lane < 64 - off) v += n;
                }
                dsuf1[lane] = v;
                if (lane == 0) { dsuf1[NCH] = 0.f; dsuf1[NCH + 1] = 0.f; }
            }
        }
    }
    __syncthreads();

    const int ql  = tid >> 3;
    const int sub = tid & 7;
    const int ln  = tid & 63;
    const int q   = qb * QB + ql;

    const float s  = sT[h * BN + b * N_ + q];
    const float A  = __expf(s);
    const float Bv = __expf(NEG * s);

    // binary search once per query group (lane sub==0), broadcast via shfl
    int p = 0;
    if (sub == 0) {
        const float tau = -s;
        int lo = 0, hi = N_;
        #pragma unroll
        for (int it = 0; it < 10; ++it) {
            int mid = (lo + hi) >> 1;
            if (tS[mid] >= tau) hi = mid; else lo = mid + 1;
        }
        p = lo;
    }
    p = __shfl(p, ln & 56);
    const int cp = p >> 4;

    // table part + uniform 16-iter boundary-chunk loop (weight select)
    float4_ acc = A  * (*reinterpret_cast<const float4_*>(&suf1[cp + 1][sub * 4]))
                + Bv * (*reinterpret_cast<const float4_*>(&pre2[cp][sub * 4]));
    float den = A * dsuf1[cp + 1] + Bv * dpre2[cp];
    if (cp < NCH) {
        #pragma unroll
        for (int jj = 0; jj < CH; ++jj) {
            const int j = (cp << 4) + jj;
            const float w = (j < p) ? Bv * e2S[j] : A * e1S[j];
            const float4_ hv = *reinterpret_cast<const float4_*>(
                &h_ws[(size_t)(b * N_ + kI[j]) * IND + h * D_ + sub * 4]);
            acc += w * hv;
            den += w;
        }
    }

    const float inv = (den > 0.f) ? 1.f / den : 0.f;
    float4_ r = acc * inv;
    *reinterpret_cast<float4_*>(&out[(size_t)(b * N_ + q) * IND + h * D_ + sub * 4]) = r;
}

extern "C" void kernel_launch(void* const* d_in, const int* in_sizes, int n_in,
                              void* d_out, int out_size, void* d_ws, size_t ws_size,
                              hipStream_t stream) {
    const float* x     = (const float*)d_in[0];
    const float* alive = (const float*)d_in[1];
    const float* W     = (const float*)d_in[2];
    const float* a_src = (const float*)d_in[3];
    const float* a_dst = (const float*)d_in[4];
    float* out = (float*)d_out;

    float*   h_ws   = (float*)d_ws;                 // BN*128 (4 MB)
    float*   sT     = h_ws + (size_t)BN * IND;      // [H][BN]
    float*   tT     = sT  + (size_t)H_ * BN;
    float*   e1T    = tT  + (size_t)H_ * BN;
    float*   e2T    = e1T + (size_t)H_ * BN;
    float4_* packed = (float4_*)(e2T + (size_t)H_ * BN);  // [32][N] x 16B
    // total ~5.5 MB

    k_gemm_alpha<<<BN / 32, 256, 0, stream>>>(x, alive, W, a_src, a_dst,
                                              h_ws, sT, tT, e1T, e2T);

    dim3 g2(N_ / 128, H_, B_);
    k_rank<<<g2, 256, 0, stream>>>(tT, e1T, e2T, packed);

    dim3 g4(N_ / QB, H_, B_);
    k_comb<<<g4, 512, 0, stream>>>(h_ws, sT, packed, out);
}

// Round 23
// 35.065 us; speedup vs baseline: 1.1018x; 1.0696x over previous
//
#include <hip/hip_runtime.h>
#include <hip/hip_bf16.h>

// GAT layer, B=8 N=1024 IN=128 H=4 D=32. Inputs f32, OUTPUT f32.
// Base = round-22 (37.5 us, = R19 best). Single change: k_rank 4-way split —
// 512 blocks x 256 thr, 4 threads/key (one table-QUARTER each, 128 ull2
// iters; quarter = wave index so LDS reads stay wave-uniform broadcasts).
// 2 blocks/CU = 2 waves/SIMD: isolates + hides the rank loop's LDS-read
// latency component (R19's superlinear gain showed it exists).
//
// kA    : h = x@W^T via MFMA 16x16x32 bf16 (x split hi+lo bf16; W bf16).
//         Epilogue: s/t/e1/e2 per (row,head) transposed [h][bn].
// k_rank: LDS-staged u64 rank, 4 threads/key, partials via LDS; scatter
//         packed{t,e1,e2,kI} into sorted order.
// k_comb: stages packed, chunk sums in-block (1 cell/thread), 8-wave
//         shuffle scan, search once per 8-lane group + uniform 16-iter
//         boundary-chunk combine (weight select), gathers via kI.

#define B_   8
#define N_   1024
#define BN   (B_ * N_)
#define IND  128
#define H_   4
#define D_   32
#define NEG  0.2f
#define CH   16
#define NCH  (N_ / CH)       // 64
#define QB   64              // queries per k_comb block

typedef float float4_ __attribute__((ext_vector_type(4)));
typedef short short8_ __attribute__((ext_vector_type(8)));

__device__ __forceinline__ float bf2f(ushort u) {
    union { unsigned int i; float f; } v; v.i = ((unsigned int)u) << 16; return v.f;
}
__device__ __forceinline__ ushort f2bf(float f) {
    union { float f; unsigned int i; } v; v.f = f;
    unsigned int lsb = (v.i >> 16) & 1u;
    v.i += 0x7fffu + lsb;
    return (ushort)(v.i >> 16);
}
__device__ __forceinline__ unsigned int orderable(float f) {
    unsigned int u = __float_as_uint(f);
    return (u & 0x80000000u) ? ~u : (u | 0x80000000u);
}
__device__ __forceinline__ short8_ pack_hi(float4_ a, float4_ b) {
    short8_ r;
    r[0] = (short)f2bf(a[0]); r[1] = (short)f2bf(a[1]);
    r[2] = (short)f2bf(a[2]); r[3] = (short)f2bf(a[3]);
    r[4] = (short)f2bf(b[0]); r[5] = (short)f2bf(b[1]);
    r[6] = (short)f2bf(b[2]); r[7] = (short)f2bf(b[3]);
    return r;
}
__device__ __forceinline__ void split_bf(float4_ a, float4_ b, short8_& hi, short8_& lo) {
    #pragma unroll
    for (int j = 0; j < 4; ++j) {
        ushort h0 = f2bf(a[j]); hi[j]     = (short)h0; lo[j]     = (short)f2bf(a[j] - bf2f(h0));
        ushort h1 = f2bf(b[j]); hi[j + 4] = (short)h1; lo[j + 4] = (short)f2bf(b[j] - bf2f(h1));
    }
}

// ---------------- Kernel A: MFMA GEMM + alpha epilogue --------------------
// grid = 256 blocks x 256 thr (4 waves). Block: 32 rows (2 M-tiles of 16).
__global__ __launch_bounds__(256) void k_gemm_alpha(
    const float* __restrict__ x,      // [B*N,128]
    const float* __restrict__ alive,  // [B*N]
    const float* __restrict__ W,      // [128,128]
    const float* __restrict__ a_src,  // [128]
    const float* __restrict__ a_dst,  // [128]
    float* __restrict__ h_ws,         // [B*N,128]
    float* __restrict__ sT,           // [H][BN]
    float* __restrict__ tT,           // [H][BN]
    float* __restrict__ e1T,          // [H][BN]
    float* __restrict__ e2T)          // [H][BN]
{
    __shared__ float hs[32][132];     // 16.9 KB
    __shared__ float asrc[IND], adst[IND];

    const int tid = threadIdx.x;
    const int wv  = tid >> 6;
    const int ln  = tid & 63;
    const int l15 = ln & 15;
    const int lg  = ln >> 4;
    const int rbase = blockIdx.x * 32;

    if (tid < IND) { asrc[tid] = a_src[tid]; adst[tid] = a_dst[tid]; }

    short8_ bf[2][4];
    #pragma unroll
    for (int t = 0; t < 2; ++t) {
        const float* wr = &W[(size_t)((wv * 2 + t) * 16 + l15) * IND + lg * 8];
        #pragma unroll
        for (int ks = 0; ks < 4; ++ks) {
            float4_ v0 = *reinterpret_cast<const float4_*>(wr + ks * 32);
            float4_ v1 = *reinterpret_cast<const float4_*>(wr + ks * 32 + 4);
            bf[t][ks] = pack_hi(v0, v1);
        }
    }

    float4_ acc[2][2];
    #pragma unroll
    for (int mt = 0; mt < 2; ++mt) {
        const float* xr = &x[(size_t)(rbase + mt * 16 + l15) * IND + lg * 8];
        short8_ ahi[4], alo[4];
        #pragma unroll
        for (int ks = 0; ks < 4; ++ks) {
            float4_ v0 = *reinterpret_cast<const float4_*>(xr + ks * 32);
            float4_ v1 = *reinterpret_cast<const float4_*>(xr + ks * 32 + 4);
            split_bf(v0, v1, ahi[ks], alo[ks]);
        }
        #pragma unroll
        for (int t = 0; t < 2; ++t) {
            float4_ a = {0.f, 0.f, 0.f, 0.f};
            #pragma unroll
            for (int ks = 0; ks < 4; ++ks) {
                a = __builtin_amdgcn_mfma_f32_16x16x32_bf16(ahi[ks], bf[t][ks], a, 0, 0, 0);
                a = __builtin_amdgcn_mfma_f32_16x16x32_bf16(alo[ks], bf[t][ks], a, 0, 0, 0);
            }
            acc[mt][t] = a;
        }
    }

    #pragma unroll
    for (int mt = 0; mt < 2; ++mt)
        #pragma unroll
        for (int t = 0; t < 2; ++t) {
            const int col = (wv * 2 + t) * 16 + l15;
            #pragma unroll
            for (int r = 0; r < 4; ++r)
                hs[mt * 16 + lg * 4 + r][col] = acc[mt][t][r];
        }
    __syncthreads();

    #pragma unroll
    for (int i = tid; i < 1024; i += 256) {
        int row = i >> 5, c4 = (i & 31) * 4;
        *reinterpret_cast<float4_*>(&h_ws[(size_t)(rbase + row) * IND + c4]) =
            *reinterpret_cast<const float4_*>(&hs[row][c4]);
    }

    if (tid < 128) {
        const int row = tid >> 2, hh = tid & 3;
        const float* hr = &hs[row][hh * 32];
        float s = 0.f, tt = 0.f;
        #pragma unroll
        for (int d = 0; d < 32; ++d) {
            s  = fmaf(hr[d], asrc[hh * 32 + d], s);
            tt = fmaf(hr[d], adst[hh * 32 + d], tt);
        }
        const int grow = rbase + row;
        const int idx  = hh * BN + grow;
        sT[idx] = s;
        tT[idx] = tt;
        float am = (alive[grow] >= 0.5f) ? 1.f : 0.f;
        e1T[idx] = am * __expf(tt);
        e2T[idx] = am * __expf(NEG * tt);
    }
}

// ---------------- Kernel 2: 4-way split rank + packed scatter -------------
// grid = (16, H, B) = 512 blocks, 256 threads. Block owns 64 keys; each key
// ranked by FOUR threads (own = tid&63, quarter = tid>>6 = wave id), each
// scanning a quarter of the staged table (128 ull2 iters, wave-uniform
// base -> broadcast LDS reads). Partials combined via LDS part[4][64].
__global__ __launch_bounds__(256) void k_rank(
    const float* __restrict__ tT,
    const float* __restrict__ e1T,
    const float* __restrict__ e2T,
    float4_* __restrict__ packed)   // [32][N] {t, e1, e2, idx}
{
    __shared__ unsigned long long keys[N_];   // 8 KB
    __shared__ int part[4][64];
    const int h = blockIdx.y, b = blockIdx.z;
    const int base = h * BN + b * N_;
    for (int i = threadIdx.x; i < N_; i += 256) {
        unsigned int u = orderable(tT[base + i]);
        keys[i] = ((unsigned long long)u << 32) | (unsigned int)i;
    }
    __syncthreads();

    const int own     = threadIdx.x & 63;
    const int quarter = threadIdx.x >> 6;   // = wave id (wave-uniform)
    const int i0      = blockIdx.x * 64 + own;
    const unsigned long long mk = keys[i0];
    int rank = 0;
    const ulonglong2* k2p = reinterpret_cast<const ulonglong2*>(keys) + quarter * 128;
    #pragma unroll 8
    for (int j = 0; j < 128; ++j) {
        ulonglong2 kk = k2p[j];           // broadcast LDS read (wave-uniform)
        rank += (int)(kk.x < mk) + (int)(kk.y < mk);
    }
    part[quarter][own] = rank;
    __syncthreads();
    if (quarter == 0) {
        rank += part[1][own] + part[2][own] + part[3][own];
        const int o = (b * H_ + h) * N_ + rank;
        float4_ pk;
        pk[0] = tT[base + i0];
        pk[1] = e1T[base + i0];
        pk[2] = e2T[base + i0];
        pk[3] = __int_as_float(i0);
        packed[o] = pk;
    }
}

// ---------------- Kernel 3: sums + scan + per-query combine ---------------
// grid = (N/QB, H, B), 512 threads: 64 queries x 8 dim-groups.
// Chunk sums computed IN-BLOCK (1 cell/thread); h gathered via kI.
__global__ __launch_bounds__(512) void k_comb(
    const float* __restrict__ h_ws,
    const float* __restrict__ sT,
    const float4_* __restrict__ packed,
    float* __restrict__ out)
{
    __shared__ float tS[N_];
    __shared__ int   kI[N_];
    __shared__ float e1S[N_], e2S[N_];
    __shared__ float pre2[NCH + 1][36];
    __shared__ float suf1[NCH + 2][36];
    __shared__ float dpre2[NCH + 1], dsuf1[NCH + 2];

    const int h = blockIdx.y, b = blockIdx.z, qb = blockIdx.x;
    const int bhi = b * H_ + h;
    const int so  = bhi * N_;
    const int tid = threadIdx.x;

    for (int i = tid; i < N_; i += 512) {
        const float4_ pk = packed[so + i];
        tS[i]  = pk[0];
        e1S[i] = pk[1];
        e2S[i] = pk[2];
        kI[i]  = __float_as_int(pk[3]);
    }
    __syncthreads();

    // chunk sums in-block: 512 threads = 512 cells (cc 0..63, dg 0..7)
    {
        const int cc = tid >> 3, dg = tid & 7;
        float4_ a1 = {0.f, 0.f, 0.f, 0.f}, a2 = {0.f, 0.f, 0.f, 0.f};
        #pragma unroll
        for (int jj = 0; jj < CH; ++jj) {
            const int j = cc * CH + jj;
            const float4_ hv = *reinterpret_cast<const float4_*>(
                &h_ws[(size_t)(b * N_ + kI[j]) * IND + h * D_ + dg * 4]);
            a1 += e1S[j] * hv;
            a2 += e2S[j] * hv;
        }
        #pragma unroll
        for (int u = 0; u < 4; ++u) {
            pre2[cc + 1][dg * 4 + u] = a2[u];
            suf1[cc][dg * 4 + u]     = a1[u];
        }
        if (tid < NCH) {
            float s2 = 0.f;
            #pragma unroll
            for (int jj = 0; jj < CH; ++jj) s2 += e2S[tid * CH + jj];
            dpre2[tid + 1] = s2;
        } else if (tid < 2 * NCH) {
            const int c2 = tid - NCH;
            float s1 = 0.f;
            #pragma unroll
            for (int jj = 0; jj < CH; ++jj) s1 += e1S[c2 * CH + jj];
            dsuf1[c2] = s1;
        }
    }
    __syncthreads();

    // in-block scans: waves 0-3 prefix, waves 4-7 suffix
    {
        const int wv = tid >> 6, lane = tid & 63;
        if (wv < 4) {
            for (int d = wv; d < D_; d += 4) {
                float v = pre2[lane + 1][d];
                #pragma unroll
                for (int off = 1; off < 64; off <<= 1) {
                    float n = __shfl_up(v, off);
                    if (lane >= off) v += n;
                }
                pre2[lane + 1][d] = v;
                if (lane == 0) pre2[0][d] = 0.f;
            }
            if (wv == 0) {
                float v = dpre2[lane + 1];
                #pragma unroll
                for (int off = 1; off < 64; off <<= 1) {
                    float n = __shfl_up(v, off);
                    if (lane >= off) v += n;
                }
                dpre2[lane + 1] = v;
                if (lane == 0) dpre2[0] = 0.f;
            }
        } else {
            for (int d = wv - 4; d < D_; d += 4) {
                float v = suf1[lane][d];
                #pragma unroll
                for (int off = 1; off < 64; off <<= 1) {
                    float n = __shfl_down(v, off);
                    if (lane < 64 - off) v += n;
                }
                suf1[lane][d] = v;
                if (lane == 0) { suf1[NCH][d] = 0.f; suf1[NCH + 1][d] = 0.f; }
            }
            if (wv == 4) {
                float v = dsuf1[lane];
                #pragma unroll
                for (int off = 1; off < 64; off <<= 1) {
                    float n = __shfl_down(v, off);
                    if (lane < 64 - off) v += n;
                }
                dsuf1[lane] = v;
                if (lane == 0) { dsuf1[NCH] = 0.f; dsuf1[NCH + 1] = 0.f; }
            }
        }
    }
    __syncthreads();

    const int ql  = tid >> 3;
    const int sub = tid & 7;
    const int ln  = tid & 63;
    const int q   = qb * QB + ql;

    const float s  = sT[h * BN + b * N_ + q];
    const float A  = __expf(s);
    const float Bv = __expf(NEG * s);

    // binary search once per query group (lane sub==0), broadcast via shfl
    int p = 0;
    if (sub == 0) {
        const float tau = -s;
        int lo = 0, hi = N_;
        #pragma unroll
        for (int it = 0; it < 10; ++it) {
            int mid = (lo + hi) >> 1;
            if (tS[mid] >= tau) hi = mid; else lo = mid + 1;
        }
        p = lo;
    }
    p = __shfl(p, ln & 56);
    const int cp = p >> 4;

    // table part + uniform 16-iter boundary-chunk loop (weight select)
    float4_ acc = A  * (*reinterpret_cast<const float4_*>(&suf1[cp + 1][sub * 4]))
                + Bv * (*reinterpret_cast<const float4_*>(&pre2[cp][sub * 4]));
    float den = A * dsuf1[cp + 1] + Bv * dpre2[cp];
    if (cp < NCH) {
        #pragma unroll
        for (int jj = 0; jj < CH; ++jj) {
            const int j = (cp << 4) + jj;
            const float w = (j < p) ? Bv * e2S[j] : A * e1S[j];
            const float4_ hv = *reinterpret_cast<const float4_*>(
                &h_ws[(size_t)(b * N_ + kI[j]) * IND + h * D_ + sub * 4]);
            acc += w * hv;
            den += w;
        }
    }

    const float inv = (den > 0.f) ? 1.f / den : 0.f;
    float4_ r = acc * inv;
    *reinterpret_cast<float4_*>(&out[(size_t)(b * N_ + q) * IND + h * D_ + sub * 4]) = r;
}

extern "C" void kernel_launch(void* const* d_in, const int* in_sizes, int n_in,
                              void* d_out, int out_size, void* d_ws, size_t ws_size,
                              hipStream_t stream) {
    const float* x     = (const float*)d_in[0];
    const float* alive = (const float*)d_in[1];
    const float* W     = (const float*)d_in[2];
    const float* a_src = (const float*)d_in[3];
    const float* a_dst = (const float*)d_in[4];
    float* out = (float*)d_out;

    float*   h_ws   = (float*)d_ws;                 // BN*128 (4 MB)
    float*   sT     = h_ws + (size_t)BN * IND;      // [H][BN]
    float*   tT     = sT  + (size_t)H_ * BN;
    float*   e1T    = tT  + (size_t)H_ * BN;
    float*   e2T    = e1T + (size_t)H_ * BN;
    float4_* packed = (float4_*)(e2T + (size_t)H_ * BN);  // [32][N] x 16B
    // total ~5.5 MB

    k_gemm_alpha<<<BN / 32, 256, 0, stream>>>(x, alive, W, a_src, a_dst,
                                              h_ws, sT, tT, e1T, e2T);

    dim3 g2(N_ / 64, H_, B_);
    k_rank<<<g2, 256, 0, stream>>>(tT, e1T, e2T, packed);

    dim3 g4(N_ / QB, H_, B_);
    k_comb<<<g4, 512, 0, stream>>>(h_ws, sT, packed, out);
}